// Round 12
// baseline (55.371 us; speedup 1.0000x reference)
//
#include <hip/hip_runtime.h>
#include <hip/hip_bf16.h>

#define IN 8192
#define OUT 8192

typedef __bf16 bf16x8 __attribute__((ext_vector_type(8)));
typedef float f32x4 __attribute__((ext_vector_type(4)));
typedef unsigned short u16;
typedef unsigned int u32;
typedef u32 u32x4 __attribute__((ext_vector_type(4)));

#define MFMA(a, b, c) __builtin_amdgcn_mfma_f32_16x16x32_bf16(a, b, c, 0, 0, 0)

static __device__ __forceinline__ u16 f2bf(float v) {
    __hip_bfloat16 h = __float2bfloat16(v);
    return __builtin_bit_cast(u16, h);
}
static __device__ __forceinline__ float bf2f(u16 h) {
    union { u32 u; float f; } cv; cv.u = ((u32)h) << 16; return cv.f;
}
static __device__ __forceinline__ void split_hl(float v, u16& hi, u16& lo) {
    hi = f2bf(v);
    lo = f2bf(v - bf2f(hi));
}
static __device__ __forceinline__ bf16x8 ld8(const u16* p) {
    return *reinterpret_cast<const bf16x8*>(p);
}

// ================= pre (R8-validated body): block (b,lc), all-coalesced global reads =================
// xp = x[b]/shw (coalesced -> LDS); X[j][n] = xp[vinp[j*128+n]] (LDS gather);
// W = X @ v2c^T; Z = v1 @ W^T; scan voutp -> sparse xt stores; Spart[b][lc].
__global__ __launch_bounds__(256)
void pre_kernel(const float* __restrict__ x, const float* __restrict__ shw,
                const int* __restrict__ vinp, const int* __restrict__ voutp,
                const float* __restrict__ v1, const float* __restrict__ v2,
                u16* __restrict__ xt, float* __restrict__ Spart) {
    __shared__ __align__(16) char smem[69632];
    __shared__ float sred[4];
    float* xp  = (float*)smem;                     // [8192] f32           [0,32768)
    u16* V1hi  = (u16*)smem;                       // overlay after X:     [0,9216)
    u16* V1lo  = (u16*)(smem + 9216);              //                      [9216,18432)
    u16* V2hi  = (u16*)(smem + 18432);             // [16][136]            [18432,22784)
    u16* V2lo  = (u16*)(smem + 22784);             //                      [22784,27136)
    u16* WThi  = (u16*)(smem + 27136);             // [16][72]             [27136,29440)
    u16* WTlo  = (u16*)(smem + 29440);             //                      [29440,31744)
    u16* Xhi   = (u16*)(smem + 32768);             // [64][136]            [32768,50176)
    u16* Xlo   = (u16*)(smem + 50176);             //                      [50176,67584)
    u16* Zl    = (u16*)(smem + 67584);             // [64][16]             [67584,69632)
    const int tid = threadIdx.x;
    const int b = blockIdx.x >> 3, lc = blockIdx.x & 7;
    const int lane = tid & 63, w = tid >> 6;
    const int l15 = lane & 15, l4 = lane >> 4;

    #pragma unroll
    for (int it = 0; it < 32; ++it) {              // coalesced x/shw -> LDS
        int q = tid + it * 256;
        xp[q] = x[b * IN + q] / shw[q];
    }
    __syncthreads();
    #pragma unroll
    for (int it = 0; it < 32; ++it) {              // X[j][n] via LDS gather
        int e = tid + it * 256;
        float v = xp[vinp[e]];
        u16 h, l; split_hl(v, h, l);
        int idx = (e >> 7) * 136 + (e & 127);
        Xhi[idx] = h; Xlo[idx] = l;
    }
    __syncthreads();                               // xp dead; overlay v1/v2c/WT
    #pragma unroll
    for (int it = 0; it < 16; ++it) {              // v1 [i][j] natural
        int e = tid + it * 256;
        u16 h, l; split_hl(v1[e], h, l);
        int idx = (e >> 6) * 72 + (e & 63);
        V1hi[idx] = h; V1lo[idx] = l;
    }
    #pragma unroll
    for (int it = 0; it < 8; ++it) {               // v2 chunk rows [r][n]
        int e = tid + it * 256;
        int r = e >> 7, n = e & 127;
        u16 h, l; split_hl(v2[(lc * 16 + r) * 128 + n], h, l);
        V2hi[r * 136 + n] = h; V2lo[r * 136 + n] = l;
    }
    __syncthreads();

    // stage A: W[j][r] = sum_n X[j,n]*v2c[r,n]  (M=64 j, N=16 r, K=128). m-tile = w.
    f32x4 acc = {0.f, 0.f, 0.f, 0.f};
    #pragma unroll
    for (int ks = 0; ks < 4; ++ks) {
        int ao = (w * 16 + l15) * 136 + ks * 32 + l4 * 8;
        int bo = l15 * 136 + ks * 32 + l4 * 8;
        bf16x8 ah = ld8(&Xhi[ao]), al = ld8(&Xlo[ao]);
        bf16x8 bh = ld8(&V2hi[bo]), bl = ld8(&V2lo[bo]);
        acc = MFMA(ah, bh, acc); acc = MFMA(ah, bl, acc); acc = MFMA(al, bh, acc);
    }
    #pragma unroll
    for (int r = 0; r < 4; ++r) {                  // W^T[r=l15][j]
        int j = w * 16 + l4 * 4 + r;
        u16 h, l; split_hl(acc[r], h, l);
        WThi[l15 * 72 + j] = h; WTlo[l15 * 72 + j] = l;
    }
    __syncthreads();

    // stage B: Z[i][r] = sum_j v1[i,j]*W^T[r,j]  (M=64 i, N=16 r, K=64). m-tile = w.
    f32x4 z = {0.f, 0.f, 0.f, 0.f};
    #pragma unroll
    for (int ks = 0; ks < 2; ++ks) {
        int ao = (w * 16 + l15) * 72 + ks * 32 + l4 * 8;
        int bo = l15 * 72 + ks * 32 + l4 * 8;
        bf16x8 ah = ld8(&V1hi[ao]), al = ld8(&V1lo[ao]);
        bf16x8 bh = ld8(&WThi[bo]), bl = ld8(&WTlo[bo]);
        z = MFMA(ah, bh, z); z = MFMA(ah, bl, z); z = MFMA(al, bh, z);
    }
    float ssum = 0.f;
    #pragma unroll
    for (int r = 0; r < 4; ++r) {
        int i = w * 16 + l4 * 4 + r;
        u16 zb = f2bf(z[r]);
        Zl[i * 16 + l15] = zb;
        ssum += bf2f(zb);
    }
    #pragma unroll
    for (int off = 32; off; off >>= 1) ssum += __shfl_down(ssum, off, 64);
    if (lane == 0) sred[w] = ssum;
    __syncthreads();
    if (tid == 0) Spart[b * 8 + lc] = (sred[0] + sred[1]) + (sred[2] + sred[3]);

    // scan voutp (coalesced); hits -> scattered 2B xt stores
    #pragma unroll
    for (int it = 0; it < 32; ++it) {
        int p = tid + it * 256;
        int v = voutp[p];
        if (((v >> 4) & 7) == lc)
            xt[(size_t)b * IN + p] = Zl[(v >> 7) * 16 + (v & 15)];
    }
}

// ================= qgemm v1 (validated, ~10 us): LDS-staged A, scalar qw loads =================
__global__ __launch_bounds__(256)
void qgemm_kernel(const int* __restrict__ qw, const u16* __restrict__ xt,
                  float* __restrict__ G) {
    __shared__ alignas(16) u16 sA[16 * 2056];
    const int tid = threadIdx.x;
    const int lane = tid & 63, w = tid >> 6;
    const int l15 = lane & 15, l4 = lane >> 4;
    const int k0 = blockIdx.y * 2048;
    #pragma unroll
    for (int i = 0; i < 16; ++i) {
        int idx = tid + i * 256;
        int r = idx >> 8, c = idx & 255;
        *reinterpret_cast<u32x4*>(&sA[r * 2056 + c * 8]) =
            *reinterpret_cast<const u32x4*>(&xt[(size_t)r * IN + k0 + c * 8]);
    }
    __syncthreads();
    const int o = blockIdx.x * 64 + w * 16 + l15;
    const int* qp = qw + (size_t)(k0 / 8 + l4) * OUT + o;
    f32x4 acc = {0.f, 0.f, 0.f, 0.f};
    #pragma unroll 8
    for (int kt = 0; kt < 64; ++kt) {
        u32 q = (u32)qp[(size_t)kt * 4 * OUT];
        bf16x8 a = ld8(&sA[l15 * 2056 + kt * 32 + l4 * 8]);
        u32 ev = q & 0x0F0F0F0Fu, od = (q >> 4) & 0x0F0F0F0Fu;
        float f0, f1, f2, f3, f4, f5, f6, f7;
        asm("v_cvt_f32_ubyte0 %0, %1" : "=v"(f0) : "v"(ev));
        asm("v_cvt_f32_ubyte0 %0, %1" : "=v"(f1) : "v"(od));
        asm("v_cvt_f32_ubyte1 %0, %1" : "=v"(f2) : "v"(ev));
        asm("v_cvt_f32_ubyte1 %0, %1" : "=v"(f3) : "v"(od));
        asm("v_cvt_f32_ubyte2 %0, %1" : "=v"(f4) : "v"(ev));
        asm("v_cvt_f32_ubyte2 %0, %1" : "=v"(f5) : "v"(od));
        asm("v_cvt_f32_ubyte3 %0, %1" : "=v"(f6) : "v"(ev));
        asm("v_cvt_f32_ubyte3 %0, %1" : "=v"(f7) : "v"(od));
        u32 p0, p1, p2, p3;
        asm("v_cvt_pk_bf16_f32 %0, %1, %2" : "=v"(p0) : "v"(f0), "v"(f1));
        asm("v_cvt_pk_bf16_f32 %0, %1, %2" : "=v"(p1) : "v"(f2), "v"(f3));
        asm("v_cvt_pk_bf16_f32 %0, %1, %2" : "=v"(p2) : "v"(f4), "v"(f5));
        asm("v_cvt_pk_bf16_f32 %0, %1, %2" : "=v"(p3) : "v"(f6), "v"(f7));
        u32x4 pk = {p0, p1, p2, p3};
        acc = MFMA(a, __builtin_bit_cast(bf16x8, pk), acc);
    }
    float* g = G + ((size_t)blockIdx.y * 16 + l4 * 4) * OUT + o;
    #pragma unroll
    for (int r = 0; r < 4; ++r) g[(size_t)r * OUT] = acc[r];
}

// ================= post (R8-validated body): block (b,lc), all-coalesced global reads =================
__global__ __launch_bounds__(256)
void post_kernel(const float* __restrict__ G, const float* __restrict__ Spart,
                 const int* __restrict__ uoutp, const int* __restrict__ uinp,
                 const float* __restrict__ scale, const float* __restrict__ u1,
                 const float* __restrict__ u2, const float* __restrict__ bias,
                 float* __restrict__ out) {
    __shared__ __align__(16) char smem[78336];
    const int tid = threadIdx.x;
    const int b = blockIdx.x >> 3, lc = blockIdx.x & 7;
    const int lane = tid & 63, w = tid >> 6;
    const int l15 = lane & 15, l4 = lane >> 4;

    u16* inv  = (u16*)smem;                        // [8192]    [0,16384)
    u16* OGhi = (u16*)(smem + 16384);              // [64][136] [16384,33792)
    u16* OGlo = (u16*)(smem + 33792);              //           [33792,51200)
    u16* U1hi = (u16*)(smem + 51200);              // [64][72]  [51200,60416)
    u16* U1lo = (u16*)(smem + 60416);              //           [60416,69632)
    u16* U2hi = (u16*)(smem + 69632);              // [16][136] [69632,73984)
    u16* U2lo = (u16*)(smem + 73984);              //           [73984,78336)
    u16* YThi = (u16*)smem;                        // overlay inv after og: [0,2304)
    u16* YTlo = (u16*)(smem + 2304);               //           [2304,4608)
    float* Zp = (float*)(smem + 4608);             // [64][16]  [4608,8704)

    float Sb = 0.f;
    #pragma unroll
    for (int c = 0; c < 8; ++c) Sb += Spart[b * 8 + c];

    #pragma unroll
    for (int it = 0; it < 32; ++it) {              // inverse of uoutp
        int e = tid + it * 256;
        inv[uoutp[e]] = (u16)e;
    }
    __syncthreads();
    #pragma unroll
    for (int it = 0; it < 32; ++it) {              // og: coalesced G/scale, LDS scatter
        int o = tid + it * 256;
        float gs = G[(size_t)b * OUT + o] + G[(size_t)(16 + b) * OUT + o]
                 + G[(size_t)(32 + b) * OUT + o] + G[(size_t)(48 + b) * OUT + o];
        float v = scale[o] * (gs * (2.0f / 15.0f) - Sb);
        int e = inv[o];
        u16 h, l; split_hl(v, h, l);
        int idx = (e >> 7) * 136 + (e & 127);
        OGhi[idx] = h; OGlo[idx] = l;
    }
    #pragma unroll
    for (int it = 0; it < 16; ++it) {              // u1^T [i][j]
        int e = tid + it * 256;
        u16 h, l; split_hl(u1[e], h, l);
        int idx = (e & 63) * 72 + (e >> 6);
        U1hi[idx] = h; U1lo[idx] = l;
    }
    #pragma unroll
    for (int it = 0; it < 8; ++it) {               // u2 col-chunk^T [lr][n]
        int e = tid + it * 256;
        int lr = e & 15, n = e >> 4;
        u16 h, l; split_hl(u2[n * 128 + lc * 16 + lr], h, l);
        U2hi[lr * 136 + n] = h; U2lo[lr * 136 + n] = l;
    }
    __syncthreads();

    // stage A': Y[j][lr] = sum_n og[j,n]*u2c[lr,n]  (M=64,N=16,K=128). m-tile = w.
    f32x4 acc = {0.f, 0.f, 0.f, 0.f};
    #pragma unroll
    for (int ks = 0; ks < 4; ++ks) {
        int ao = (w * 16 + l15) * 136 + ks * 32 + l4 * 8;
        int bo = l15 * 136 + ks * 32 + l4 * 8;
        bf16x8 ah = ld8(&OGhi[ao]), al = ld8(&OGlo[ao]);
        bf16x8 bh = ld8(&U2hi[bo]), bl = ld8(&U2lo[bo]);
        acc = MFMA(ah, bh, acc); acc = MFMA(ah, bl, acc); acc = MFMA(al, bh, acc);
    }
    #pragma unroll
    for (int r = 0; r < 4; ++r) {                  // Y^T[lr=l15][j]
        int j = w * 16 + l4 * 4 + r;
        u16 h, l; split_hl(acc[r], h, l);
        YThi[l15 * 72 + j] = h; YTlo[l15 * 72 + j] = l;
    }
    __syncthreads();

    // stage B': Zp[i][lr] = sum_j u1T[i,j]*Y^T[lr,j]  (M=64,N=16,K=64). m-tile = w.
    f32x4 z = {0.f, 0.f, 0.f, 0.f};
    #pragma unroll
    for (int ks = 0; ks < 2; ++ks) {
        int ao = (w * 16 + l15) * 72 + ks * 32 + l4 * 8;
        int bo = l15 * 72 + ks * 32 + l4 * 8;
        bf16x8 ah = ld8(&U1hi[ao]), al = ld8(&U1lo[ao]);
        bf16x8 bh = ld8(&YThi[bo]), bl = ld8(&YTlo[bo]);
        z = MFMA(ah, bh, z); z = MFMA(ah, bl, z); z = MFMA(al, bh, z);
    }
    #pragma unroll
    for (int r = 0; r < 4; ++r)
        Zp[(w * 16 + l4 * 4 + r) * 16 + l15] = z[r];
    __syncthreads();

    #pragma unroll
    for (int it = 0; it < 32; ++it) {              // scan uinp + coalesced bias
        int p = tid + it * 256;
        int u = uinp[p];
        float bv = bias[p];
        if (((u >> 4) & 7) == lc)
            out[(size_t)b * OUT + p] = Zp[(u >> 7) * 16 + (u & 15)] + bv;
    }
}

extern "C" void kernel_launch(void* const* d_in, const int* in_sizes, int n_in,
                              void* d_out, int out_size, void* d_ws, size_t ws_size,
                              hipStream_t stream) {
    const float* x     = (const float*)d_in[0];
    const int*   qw    = (const int*)d_in[1];
    const float* scale = (const float*)d_in[2];
    const float* shw   = (const float*)d_in[3];
    const float* v1    = (const float*)d_in[4];
    const float* v2    = (const float*)d_in[5];
    const float* u1    = (const float*)d_in[6];
    const float* u2    = (const float*)d_in[7];
    const float* bias  = (const float*)d_in[8];
    const int* vinp  = (const int*)d_in[9];
    const int* voutp = (const int*)d_in[10];
    const int* uinp  = (const int*)d_in[11];
    const int* uoutp = (const int*)d_in[12];
    float* out = (float*)d_out;

    char* ws = (char*)d_ws;
    u16*   xt    = (u16*)ws;                       // 256 KiB  [16][8192] bf16
    float* G     = (float*)(ws + (256 << 10));     // 2 MiB    [4][16][8192] f32
    float* Spart = (float*)(ws + (2304 << 10));    // 512 B    [16][8]

    pre_kernel<<<128, 256, 0, stream>>>(x, shw, vinp, voutp, v1, v2, xt, Spart);
    qgemm_kernel<<<dim3(128, 4), 256, 0, stream>>>(qw, xt, G);
    post_kernel<<<128, 256, 0, stream>>>(G, Spart, uoutp, uinp, scale, u1, u2, bias, out);
}

// Round 13
// 35.891 us; speedup vs baseline: 1.5428x; 1.5428x over previous
//
#include <hip/hip_runtime.h>
#include <hip/hip_bf16.h>

#define IN 8192
#define OUT 8192

typedef __bf16 bf16x8 __attribute__((ext_vector_type(8)));
typedef float f32x4 __attribute__((ext_vector_type(4)));
typedef unsigned short u16;
typedef unsigned int u32;
typedef u32 u32x4 __attribute__((ext_vector_type(4)));

#define MFMA(a, b, c) __builtin_amdgcn_mfma_f32_16x16x32_bf16(a, b, c, 0, 0, 0)

static __device__ __forceinline__ u16 f2bf(float v) {
    __hip_bfloat16 h = __float2bfloat16(v);
    return __builtin_bit_cast(u16, h);
}
static __device__ __forceinline__ float bf2f(u16 h) {
    union { u32 u; float f; } cv; cv.u = ((u32)h) << 16; return cv.f;
}
static __device__ __forceinline__ void split_hl(float v, u16& hi, u16& lo) {
    hi = f2bf(v);
    lo = f2bf(v - bf2f(hi));
}
static __device__ __forceinline__ bf16x8 ld8(const u16* p) {
    return *reinterpret_cast<const bf16x8*>(p);
}

// ======== pre1: block (b,nc): T[:,16nc:+16] = v1 @ X[:,chunk]; also invv/invu build ========
__global__ __launch_bounds__(256)
void pre1_kernel(const float* __restrict__ x, const float* __restrict__ shw,
                 const int* __restrict__ vinp, const int* __restrict__ voutp,
                 const int* __restrict__ uinp, const float* __restrict__ v1,
                 u16* __restrict__ Thi_g, u16* __restrict__ Tlo_g,
                 int* __restrict__ invv, int* __restrict__ invu) {
    __shared__ alignas(16) u16 sV1[2][64 * 72];    // v1 hi/lo [i][j] stride 72
    __shared__ alignas(16) u16 sX[2][16 * 72];     // X^T chunk [n][j] stride 72
    const int tid = threadIdx.x, bid = blockIdx.x;
    const int b = bid >> 3, nc = bid & 7;
    const int lane = tid & 63, w = tid >> 6;
    const int l15 = lane & 15, l4 = lane >> 4;

    if (tid < 64) {                                // disjoint 64-entry slice of each inverse perm
        int e = bid * 64 + tid;
        invv[voutp[e]] = e;
        invu[uinp[e]] = e;
    }
    #pragma unroll
    for (int it = 0; it < 16; ++it) {              // v1: 4096, [i][j]
        int e = tid + it * 256;
        u16 h, l; split_hl(v1[e], h, l);
        int idx = (e >> 6) * 72 + (e & 63);
        sV1[0][idx] = h; sV1[1][idx] = l;
    }
    #pragma unroll
    for (int it = 0; it < 4; ++it) {               // X chunk gather (1024, disjoint per block)
        int e = tid + it * 256;                    // e = j*16 + nn
        int j = e >> 4, nn = e & 15;
        int gi = vinp[j * 128 + nc * 16 + nn];
        float v = x[b * IN + gi] / shw[gi];
        u16 h, l; split_hl(v, h, l);
        int idx = nn * 72 + j;                     // X^T [nn][j]
        sX[0][idx] = h; sX[1][idx] = l;
    }
    __syncthreads();

    // T chunk = v1 @ Xc  (M=64 -> wave m-tile, N=16, K=64)
    f32x4 acc = {0.f, 0.f, 0.f, 0.f};
    #pragma unroll
    for (int ks = 0; ks < 2; ++ks) {
        int bo = l15 * 72 + ks * 32 + l4 * 8;
        bf16x8 bh = ld8(&sX[0][bo]), bl = ld8(&sX[1][bo]);
        int ao = (w * 16 + l15) * 72 + ks * 32 + l4 * 8;
        bf16x8 ah = ld8(&sV1[0][ao]), al = ld8(&sV1[1][ao]);
        acc = MFMA(ah, bh, acc); acc = MFMA(ah, bl, acc); acc = MFMA(al, bh, acc);
    }
    #pragma unroll
    for (int r = 0; r < 4; ++r) {
        int i = w * 16 + l4 * 4 + r;
        u16 h, l; split_hl(acc[r], h, l);
        size_t off = ((size_t)b * 64 + i) * 128 + nc * 16 + l15;
        Thi_g[off] = h; Tlo_g[off] = l;
    }
}

// ======== pre2: block (b,lc): Z[:,16lc:+16] = T @ v2c^T -> scatter xt + Spart ========
__global__ __launch_bounds__(256)
void pre2_kernel(const u16* __restrict__ Thi_g, const u16* __restrict__ Tlo_g,
                 const float* __restrict__ v2, const int* __restrict__ invv,
                 u16* __restrict__ xt, float* __restrict__ Spart) {
    __shared__ alignas(16) u16 sT[2][64 * 136];    // T hi/lo [i][k] stride 136
    __shared__ alignas(16) u16 sV2[2][16 * 136];   // v2 chunk [r][k] stride 136
    __shared__ float sred[4];
    const int tid = threadIdx.x, bid = blockIdx.x;
    const int b = bid >> 3, lc = bid & 7;
    const int lane = tid & 63, w = tid >> 6;
    const int l15 = lane & 15, l4 = lane >> 4;

    #pragma unroll
    for (int it = 0; it < 4; ++it) {               // T load coalesced 16B (1024 chunks each)
        int e = tid + it * 256;
        int i = e >> 4, k = (e & 15) * 8;
        size_t off = ((size_t)b * 64 + i) * 128 + k;
        *reinterpret_cast<u32x4*>(&sT[0][i * 136 + k]) =
            *reinterpret_cast<const u32x4*>(&Thi_g[off]);
        *reinterpret_cast<u32x4*>(&sT[1][i * 136 + k]) =
            *reinterpret_cast<const u32x4*>(&Tlo_g[off]);
    }
    #pragma unroll
    for (int it = 0; it < 8; ++it) {               // v2 chunk rows
        int e = tid + it * 256;                    // r*128 + k
        int r = e >> 7, k = e & 127;
        u16 h, l; split_hl(v2[(lc * 16 + r) * 128 + k], h, l);
        sV2[0][r * 136 + k] = h; sV2[1][r * 136 + k] = l;
    }
    __syncthreads();

    // Z chunk = T @ v2c^T  (M=64 -> wave m-tile, N=16, K=128)
    f32x4 z = {0.f, 0.f, 0.f, 0.f};
    #pragma unroll
    for (int ks = 0; ks < 4; ++ks) {
        int bo = l15 * 136 + ks * 32 + l4 * 8;
        bf16x8 bh = ld8(&sV2[0][bo]), bl = ld8(&sV2[1][bo]);
        int ao = (w * 16 + l15) * 136 + ks * 32 + l4 * 8;
        bf16x8 ah = ld8(&sT[0][ao]), al = ld8(&sT[1][ao]);
        z = MFMA(ah, bh, z); z = MFMA(ah, bl, z); z = MFMA(al, bh, z);
    }
    float ssum = 0.f;
    #pragma unroll
    for (int r = 0; r < 4; ++r) {
        int i = w * 16 + l4 * 4 + r;
        int q = i * 128 + lc * 16 + l15;
        u16 zb = f2bf(z[r]);
        xt[(size_t)b * IN + invv[q]] = zb;
        ssum += bf2f(zb);
    }
    #pragma unroll
    for (int off = 32; off; off >>= 1) ssum += __shfl_down(ssum, off, 64);
    if (lane == 0) sred[w] = ssum;
    __syncthreads();
    if (tid == 0) Spart[b * 8 + lc] = (sred[0] + sred[1]) + (sred[2] + sred[3]);
}

// ======== qgemm v4 (R6/R7-validated 8-wave form): 16 waves/CU, 32KB qw in flight ========
__global__ __launch_bounds__(512)
void qgemm_kernel(const int* __restrict__ qw, const u16* __restrict__ xt,
                  float* __restrict__ G) {
    __shared__ alignas(16) u16 sA[16 * 2056];
    const int tid = threadIdx.x;
    const int lane = tid & 63, w = tid >> 6;
    const int l15 = lane & 15, l4 = lane >> 4;
    const int o0 = blockIdx.x * 128, k0 = blockIdx.y * 2048;
    #pragma unroll
    for (int it = 0; it < 8; ++it) {
        int idx = it * 512 + tid;                  // 0..4095
        int r = idx >> 8, c = idx & 255;
        *reinterpret_cast<u32x4*>(&sA[r * 2056 + c * 8]) =
            *reinterpret_cast<const u32x4*>(&xt[(size_t)r * IN + k0 + c * 8]);
    }
    __syncthreads();
    const int o = o0 + w * 16 + l15;
    const int* qp = qw + (size_t)(k0 / 8 + l4) * OUT + o;
    f32x4 acc = {0.f, 0.f, 0.f, 0.f};
    #pragma unroll 8
    for (int kt = 0; kt < 64; ++kt) {
        u32 q = (u32)qp[(size_t)kt * 4 * OUT];
        bf16x8 a = ld8(&sA[l15 * 2056 + kt * 32 + l4 * 8]);
        u32 ev = q & 0x0F0F0F0Fu, od = (q >> 4) & 0x0F0F0F0Fu;
        float f0, f1, f2, f3, f4, f5, f6, f7;
        asm("v_cvt_f32_ubyte0 %0, %1" : "=v"(f0) : "v"(ev));
        asm("v_cvt_f32_ubyte0 %0, %1" : "=v"(f1) : "v"(od));
        asm("v_cvt_f32_ubyte1 %0, %1" : "=v"(f2) : "v"(ev));
        asm("v_cvt_f32_ubyte1 %0, %1" : "=v"(f3) : "v"(od));
        asm("v_cvt_f32_ubyte2 %0, %1" : "=v"(f4) : "v"(ev));
        asm("v_cvt_f32_ubyte2 %0, %1" : "=v"(f5) : "v"(od));
        asm("v_cvt_f32_ubyte3 %0, %1" : "=v"(f6) : "v"(ev));
        asm("v_cvt_f32_ubyte3 %0, %1" : "=v"(f7) : "v"(od));
        u32 p0, p1, p2, p3;
        asm("v_cvt_pk_bf16_f32 %0, %1, %2" : "=v"(p0) : "v"(f0), "v"(f1));
        asm("v_cvt_pk_bf16_f32 %0, %1, %2" : "=v"(p1) : "v"(f2), "v"(f3));
        asm("v_cvt_pk_bf16_f32 %0, %1, %2" : "=v"(p2) : "v"(f4), "v"(f5));
        asm("v_cvt_pk_bf16_f32 %0, %1, %2" : "=v"(p3) : "v"(f6), "v"(f7));
        u32x4 pk = {p0, p1, p2, p3};
        acc = MFMA(a, __builtin_bit_cast(bf16x8, pk), acc);
    }
    float* g = G + ((size_t)blockIdx.y * 16 + l4 * 4) * OUT + o;
    #pragma unroll
    for (int r = 0; r < 4; ++r) g[(size_t)r * OUT] = acc[r];
}

// ======== post1: block (b,nc): t2[:,16nc:+16] = u1^T @ og[:,chunk] ========
__global__ __launch_bounds__(256)
void post1_kernel(const float* __restrict__ G, const float* __restrict__ Spart,
                  const int* __restrict__ uoutp, const float* __restrict__ scale,
                  const float* __restrict__ u1,
                  u16* __restrict__ t2hi_g, u16* __restrict__ t2lo_g) {
    __shared__ alignas(16) u16 sU1[2][64 * 72];    // u1^T [i][j] stride 72
    __shared__ alignas(16) u16 sOG[2][16 * 72];    // og^T chunk [n][j] stride 72
    const int tid = threadIdx.x, bid = blockIdx.x;
    const int b = bid >> 3, nc = bid & 7;
    const int lane = tid & 63, w = tid >> 6;
    const int l15 = lane & 15, l4 = lane >> 4;

    float Sb = 0.f;
    #pragma unroll
    for (int c = 0; c < 8; ++c) Sb += Spart[b * 8 + c];

    #pragma unroll
    for (int it = 0; it < 16; ++it) {              // u1^T: u1[j*64+i] -> [i][j]
        int e = tid + it * 256;
        u16 h, l; split_hl(u1[e], h, l);
        int idx = (e & 63) * 72 + (e >> 6);
        sU1[0][idx] = h; sU1[1][idx] = l;
    }
    #pragma unroll
    for (int it = 0; it < 4; ++it) {               // og chunk gather (disjoint per block)
        int e = tid + it * 256;                    // e = j*16 + nn
        int j = e >> 4, nn = e & 15;
        int o = uoutp[j * 128 + nc * 16 + nn];
        float gs = G[(size_t)b * OUT + o] + G[(size_t)(16 + b) * OUT + o]
                 + G[(size_t)(32 + b) * OUT + o] + G[(size_t)(48 + b) * OUT + o];
        float v = scale[o] * (gs * (2.0f / 15.0f) - Sb);
        u16 h, l; split_hl(v, h, l);
        int idx = nn * 72 + j;
        sOG[0][idx] = h; sOG[1][idx] = l;
    }
    __syncthreads();

    // t2 chunk = u1^T @ ogc  (M=64 -> wave m-tile, N=16, K=64)
    f32x4 acc = {0.f, 0.f, 0.f, 0.f};
    #pragma unroll
    for (int ks = 0; ks < 2; ++ks) {
        int bo = l15 * 72 + ks * 32 + l4 * 8;
        bf16x8 bh = ld8(&sOG[0][bo]), bl = ld8(&sOG[1][bo]);
        int ao = (w * 16 + l15) * 72 + ks * 32 + l4 * 8;
        bf16x8 ah = ld8(&sU1[0][ao]), al = ld8(&sU1[1][ao]);
        acc = MFMA(ah, bh, acc); acc = MFMA(ah, bl, acc); acc = MFMA(al, bh, acc);
    }
    #pragma unroll
    for (int r = 0; r < 4; ++r) {
        int i = w * 16 + l4 * 4 + r;
        u16 h, l; split_hl(acc[r], h, l);
        size_t off = ((size_t)b * 64 + i) * 128 + nc * 16 + l15;
        t2hi_g[off] = h; t2lo_g[off] = l;
    }
}

// ======== post2: block (b,lc): Zp[:,16lc:+16] = t2 @ u2c -> out + bias ========
__global__ __launch_bounds__(256)
void post2_kernel(const u16* __restrict__ t2hi_g, const u16* __restrict__ t2lo_g,
                  const float* __restrict__ u2, const int* __restrict__ invu,
                  const float* __restrict__ bias, float* __restrict__ out) {
    __shared__ alignas(16) u16 sT[2][64 * 136];    // t2 hi/lo [i][k] stride 136
    __shared__ alignas(16) u16 sU2[2][16 * 136];   // u2 col-chunk [r][k] stride 136
    const int tid = threadIdx.x, bid = blockIdx.x;
    const int b = bid >> 3, lc = bid & 7;
    const int lane = tid & 63, w = tid >> 6;
    const int l15 = lane & 15, l4 = lane >> 4;

    #pragma unroll
    for (int it = 0; it < 4; ++it) {               // t2 load coalesced 16B
        int e = tid + it * 256;
        int i = e >> 4, k = (e & 15) * 8;
        size_t off = ((size_t)b * 64 + i) * 128 + k;
        *reinterpret_cast<u32x4*>(&sT[0][i * 136 + k]) =
            *reinterpret_cast<const u32x4*>(&t2hi_g[off]);
        *reinterpret_cast<u32x4*>(&sT[1][i * 136 + k]) =
            *reinterpret_cast<const u32x4*>(&t2lo_g[off]);
    }
    #pragma unroll
    for (int it = 0; it < 8; ++it) {               // u2 col-chunk: u2[k][16lc+r] -> [r][k]
        int e = tid + it * 256;                    // e = k*16 + r
        int k = e >> 4, r = e & 15;
        u16 h, l; split_hl(u2[k * 128 + lc * 16 + r], h, l);
        sU2[0][r * 136 + k] = h; sU2[1][r * 136 + k] = l;
    }
    __syncthreads();

    // Zp chunk = t2 @ u2c  (M=64 -> wave m-tile, N=16, K=128)
    f32x4 z = {0.f, 0.f, 0.f, 0.f};
    #pragma unroll
    for (int ks = 0; ks < 4; ++ks) {
        int bo = l15 * 136 + ks * 32 + l4 * 8;
        bf16x8 bh = ld8(&sU2[0][bo]), bl = ld8(&sU2[1][bo]);
        int ao = (w * 16 + l15) * 136 + ks * 32 + l4 * 8;
        bf16x8 ah = ld8(&sT[0][ao]), al = ld8(&sT[1][ao]);
        z = MFMA(ah, bh, z); z = MFMA(ah, bl, z); z = MFMA(al, bh, z);
    }
    #pragma unroll
    for (int r = 0; r < 4; ++r) {
        int i = w * 16 + l4 * 4 + r;
        int q = i * 128 + lc * 16 + l15;
        int p = invu[q];
        out[(size_t)b * OUT + p] = z[r] + bias[p];
    }
}

extern "C" void kernel_launch(void* const* d_in, const int* in_sizes, int n_in,
                              void* d_out, int out_size, void* d_ws, size_t ws_size,
                              hipStream_t stream) {
    const float* x     = (const float*)d_in[0];
    const int*   qw    = (const int*)d_in[1];
    const float* scale = (const float*)d_in[2];
    const float* shw   = (const float*)d_in[3];
    const float* v1    = (const float*)d_in[4];
    const float* v2    = (const float*)d_in[5];
    const float* u1    = (const float*)d_in[6];
    const float* u2    = (const float*)d_in[7];
    const float* bias  = (const float*)d_in[8];
    const int* vinp  = (const int*)d_in[9];
    const int* voutp = (const int*)d_in[10];
    const int* uinp  = (const int*)d_in[11];
    const int* uoutp = (const int*)d_in[12];
    float* out = (float*)d_out;

    char* ws = (char*)d_ws;
    u16*   xt    = (u16*)ws;                       // 256 KiB  [16][8192] bf16
    float* G     = (float*)(ws + (256 << 10));     // 2 MiB    [4][16][8192] f32
    float* Spart = (float*)(ws + (2304 << 10));    // 512 B    [16][8]
    int*   invv  = (int*)(ws + (2305 << 10));      // 32 KiB
    int*   invu  = (int*)(ws + (2337 << 10));      // 32 KiB
    u16*   Thi   = (u16*)(ws + (2369 << 10));      // 256 KiB  [16][64][128]
    u16*   Tlo   = (u16*)(ws + (2625 << 10));      // 256 KiB
    u16*   t2hi  = (u16*)(ws + (2881 << 10));      // 256 KiB
    u16*   t2lo  = (u16*)(ws + (3137 << 10));      // 256 KiB

    pre1_kernel<<<128, 256, 0, stream>>>(x, shw, vinp, voutp, uinp, v1, Thi, Tlo, invv, invu);
    pre2_kernel<<<128, 256, 0, stream>>>(Thi, Tlo, v2, invv, xt, Spart);
    qgemm_kernel<<<dim3(64, 4), 512, 0, stream>>>(qw, xt, G);
    post1_kernel<<<128, 256, 0, stream>>>(G, Spart, uoutp, scale, u1, t2hi, t2lo);
    post2_kernel<<<128, 256, 0, stream>>>(t2hi, t2lo, u2, invu, bias, out);
}